// Round 1
// baseline (467.179 us; speedup 1.0000x reference)
//
#include <hip/hip_runtime.h>

typedef unsigned short ushort_t;
typedef __attribute__((ext_vector_type(8))) short short8;
typedef __attribute__((ext_vector_type(4))) float floatx4;

// ---------- helpers ----------

__device__ __forceinline__ ushort_t f2bf(float f) {
    unsigned int u = __float_as_uint(f);
    u = (u + 0x7FFFu + ((u >> 16) & 1u)) >> 16;   // round-to-nearest-even
    return (ushort_t)u;
}

typedef __attribute__((address_space(1))) void gls_g;
typedef __attribute__((address_space(3))) void gls_l;

__device__ __forceinline__ void async_copy16(const ushort_t* g, ushort_t* l) {
    // global -> LDS direct DMA, 16B per lane; LDS dest = wave-uniform base + lane*16
    __builtin_amdgcn_global_load_lds((gls_g*)g, (gls_l*)l, 16, 0, 0);
}

__device__ __forceinline__ floatx4 mfma16(short8 a, short8 b, floatx4 c) {
    return __builtin_amdgcn_mfma_f32_16x16x32_bf16(a, b, c, 0, 0, 0);
}

// ---------- fp32 -> bf16 convert ----------

__global__ __launch_bounds__(256) void conv_bf16(const float* __restrict__ in,
                                                 ushort_t* __restrict__ out, int n) {
    int i = (blockIdx.x * 256 + threadIdx.x) * 4;
    if (i < n) {
        float4 f = *(const float4*)(in + i);
        ushort4 o;
        o.x = f2bf(f.x); o.y = f2bf(f.y); o.z = f2bf(f.z); o.w = f2bf(f.w);
        *(ushort4*)(out + i) = o;
    }
}

// ---------- GEMM: C[M,N] = A[M,K] @ B[N,K]^T  (both row-major, K inner) ----------
// 128x128 tile, BK=32, 256 threads = 4 waves, each wave 64x64 (4x4 MFMA tiles).

template<int BF16_OUT>
__global__ __launch_bounds__(256, 2) void gemm_nt(const ushort_t* __restrict__ A,
                                                  const ushort_t* __restrict__ B,
                                                  void* __restrict__ Cv,
                                                  const float* __restrict__ bias,
                                                  int M, int N, int K, int ldc) {
    __shared__ ushort_t lA[128 * 32];
    __shared__ ushort_t lB[128 * 32];
    const int tid  = threadIdx.x;
    const int wave = tid >> 6, lane = tid & 63;
    const int quad = lane >> 4, l15 = lane & 15;
    const int wr = (wave >> 1) * 64;   // wave row offset in tile
    const int wc = (wave & 1) * 64;    // wave col offset in tile
    const size_t bm = blockIdx.y, bn = blockIdx.x;

    const ushort_t* Ab = A + bm * 128 * (size_t)K;
    const ushort_t* Bb = B + bn * 128 * (size_t)K;

    floatx4 acc[4][4];
#pragma unroll
    for (int i = 0; i < 4; ++i)
#pragma unroll
        for (int j = 0; j < 4; ++j) acc[i][j] = (floatx4){0.f, 0.f, 0.f, 0.f};

    for (int kt = 0; kt < K; kt += 32) {
        __syncthreads();                       // prior LDS reads done
#pragma unroll
        for (int i = 0; i < 2; ++i) {
            const int li  = i * 256 + tid;     // chunk id: LDS linear off = li*16B
            const int row = li >> 2;
            const int ko  = (li & 3) * 8;
            async_copy16(Ab + (size_t)row * K + kt + ko, &lA[i * 2048 + wave * 512]);
            async_copy16(Bb + (size_t)row * K + kt + ko, &lB[i * 2048 + wave * 512]);
        }
        __syncthreads();                       // drains vmcnt(0) for the DMA

        short8 af[4], bf[4];
#pragma unroll
        for (int mt = 0; mt < 4; ++mt)
            af[mt] = *(const short8*)&lA[(wr + mt * 16 + l15) * 32 + quad * 8];
#pragma unroll
        for (int nt = 0; nt < 4; ++nt)
            bf[nt] = *(const short8*)&lB[(wc + nt * 16 + l15) * 32 + quad * 8];
#pragma unroll
        for (int mt = 0; mt < 4; ++mt)
#pragma unroll
            for (int nt = 0; nt < 4; ++nt)
                acc[mt][nt] = mfma16(af[mt], bf[nt], acc[mt][nt]);
    }

#pragma unroll
    for (int mt = 0; mt < 4; ++mt)
#pragma unroll
        for (int nt = 0; nt < 4; ++nt)
#pragma unroll
            for (int r = 0; r < 4; ++r) {
                const size_t m = bm * 128 + wr + mt * 16 + quad * 4 + r;
                const size_t n = bn * 128 + wc + nt * 16 + l15;
                const float v = acc[mt][nt][r];
                if (BF16_OUT)
                    ((ushort_t*)Cv)[m * (size_t)ldc + n] = f2bf(v);
                else
                    ((float*)Cv)[m * (size_t)ldc + n] = v + bias[n];
            }
}

// ---------- V transpose: qkv V block [b][s][h][dv] -> vt[b][h][dv][s] ----------

__global__ __launch_bounds__(256) void transpose_v(const ushort_t* __restrict__ qkv,
                                                   ushort_t* __restrict__ vt) {
    const int bh = blockIdx.y, b = bh >> 4, h = bh & 15;
    const int st = blockIdx.x;                 // s-tile of 64
    const int t  = threadIdx.x;
    const int sl  = t >> 2;                    // 0..63
    const int dv0 = (t & 3) * 16;              // 0,16,32,48
    const int s = st * 64 + sl;
    const ushort_t* src = qkv + (size_t)(b * 2048 + s) * 3072 + 2048 + h * 64 + dv0;
    ushort_t v[16];
    *(uint4*)&v[0] = *(const uint4*)src;
    *(uint4*)&v[8] = *(const uint4*)(src + 8);
    ushort_t* dst = vt + (size_t)((b * 16 + h) * 64) * 2048 + s;
#pragma unroll
    for (int i = 0; i < 16; ++i) dst[(size_t)(dv0 + i) * 2048] = v[i];
}

// ---------- flash attention (causal), 1 wave = 32 q rows, waves independent ----------

__global__ __launch_bounds__(256, 2) void attn_fwd(const ushort_t* __restrict__ qkv,
                                                   const ushort_t* __restrict__ vt,
                                                   ushort_t* __restrict__ attn) {
    __shared__ ushort_t lP[4][512];            // per-wave 16x32 bf16 P buffer
    const int tid = threadIdx.x, wave = tid >> 6, lane = tid & 63;
    const int quad = lane >> 4, l15 = lane & 15;
    const int bh = blockIdx.y, b = bh >> 4, h = bh & 15;
    const int qx = (gridDim.x - 1) - blockIdx.x;   // long blocks first
    const int q0 = qx * 128 + wave * 32;

    const ushort_t* qb = qkv + (size_t)b * 2048 * 3072 + h * 64;
    const ushort_t* kb = qb + 1024;
    const ushort_t* vb = vt + (size_t)((b * 16 + h) * 64) * 2048;
    ushort_t* P = lP[wave];

    short8 qf[2][2];                           // [mt][kstep]
#pragma unroll
    for (int mt = 0; mt < 2; ++mt)
#pragma unroll
        for (int ks = 0; ks < 2; ++ks)
            qf[mt][ks] = *(const short8*)(qb + (size_t)(q0 + mt * 16 + l15) * 3072 +
                                          ks * 32 + quad * 8);

    floatx4 ao[2][4];
    float ms[2][4], ls[2][4];
#pragma unroll
    for (int mt = 0; mt < 2; ++mt) {
#pragma unroll
        for (int ns = 0; ns < 4; ++ns) ao[mt][ns] = (floatx4){0.f, 0.f, 0.f, 0.f};
#pragma unroll
        for (int r = 0; r < 4; ++r) { ms[mt][r] = -INFINITY; ls[mt][r] = 0.f; }
    }

    const int nkt = q0 / 32 + 1;
    for (int ti = 0; ti < nkt; ++ti) {
        short8 kf[2][2];                       // [ksub][kstep]
#pragma unroll
        for (int ksub = 0; ksub < 2; ++ksub)
#pragma unroll
            for (int ks = 0; ks < 2; ++ks)
                kf[ksub][ks] = *(const short8*)(kb +
                    (size_t)(ti * 32 + ksub * 16 + l15) * 3072 + ks * 32 + quad * 8);
        short8 vf[4];                          // [nsub] from transposed V
#pragma unroll
        for (int ns = 0; ns < 4; ++ns)
            vf[ns] = *(const short8*)(vb + (size_t)(ns * 16 + l15) * 2048 +
                                      ti * 32 + quad * 8);

        const bool diag = (ti == nkt - 1);
#pragma unroll
        for (int mt = 0; mt < 2; ++mt) {
            const floatx4 z = {0.f, 0.f, 0.f, 0.f};
            floatx4 s0 = mfma16(qf[mt][0], kf[0][0], z);
            s0 = mfma16(qf[mt][1], kf[0][1], s0);
            floatx4 s1 = mfma16(qf[mt][0], kf[1][0], z);
            s1 = mfma16(qf[mt][1], kf[1][1], s1);
#pragma unroll
            for (int r = 0; r < 4; ++r) {
                const int qrow = mt * 16 + quad * 4 + r;   // row rel. to q0
                float a0 = s0[r] * 0.125f, a1 = s1[r] * 0.125f;
                if (diag) {                    // diag tile keys rel = l15 / 16+l15
                    if (l15 > qrow)      a0 = -INFINITY;
                    if (16 + l15 > qrow) a1 = -INFINITY;
                }
                float rmax = fmaxf(a0, a1);
                rmax = fmaxf(rmax, __shfl_xor(rmax, 1));
                rmax = fmaxf(rmax, __shfl_xor(rmax, 2));
                rmax = fmaxf(rmax, __shfl_xor(rmax, 4));
                rmax = fmaxf(rmax, __shfl_xor(rmax, 8));
                const float mold = ms[mt][r];
                const float mnew = fmaxf(mold, rmax);
                const float alpha = __expf(mold - mnew);   // exp(-inf)=0 first tile
                ms[mt][r] = mnew;
                const float p0 = __expf(a0 - mnew), p1 = __expf(a1 - mnew);
                float rsum = p0 + p1;
                rsum += __shfl_xor(rsum, 1);
                rsum += __shfl_xor(rsum, 2);
                rsum += __shfl_xor(rsum, 4);
                rsum += __shfl_xor(rsum, 8);
                ls[mt][r] = ls[mt][r] * alpha + rsum;
#pragma unroll
                for (int ns = 0; ns < 4; ++ns) ao[mt][ns][r] *= alpha;
                // P: D-layout -> LDS (row-major 16x32)
                P[(quad * 4 + r) * 32 + l15]      = f2bf(p0);
                P[(quad * 4 + r) * 32 + 16 + l15] = f2bf(p1);
            }
            __builtin_amdgcn_s_waitcnt(0xc07f);            // lgkmcnt(0)
            const short8 pf = *(const short8*)&P[l15 * 32 + quad * 8];  // A-layout
#pragma unroll
            for (int ns = 0; ns < 4; ++ns) ao[mt][ns] = mfma16(pf, vf[ns], ao[mt][ns]);
        }
    }

#pragma unroll
    for (int mt = 0; mt < 2; ++mt)
#pragma unroll
        for (int r = 0; r < 4; ++r) {
            const float inv = 1.0f / ls[mt][r];
            const int s = q0 + mt * 16 + quad * 4 + r;
            ushort_t* orow = attn + (size_t)(b * 2048 + s) * 1024 + h * 64 + l15;
#pragma unroll
            for (int ns = 0; ns < 4; ++ns)
                orow[ns * 16] = f2bf(ao[mt][ns][r] * inv);
        }
}

// ---------- launch ----------

extern "C" void kernel_launch(void* const* d_in, const int* in_sizes, int n_in,
                              void* d_out, int out_size, void* d_ws, size_t ws_size,
                              hipStream_t stream) {
    const float* x  = (const float*)d_in[0];
    const float* wq = (const float*)d_in[1];
    const float* wk = (const float*)d_in[2];
    const float* wv = (const float*)d_in[3];
    const float* wo = (const float*)d_in[4];
    const float* bo = (const float*)d_in[5];

    char* ws = (char*)d_ws;
    // ws layout (bytes):
    //   [0,          16777216)  x bf16            [8192][1024]  (reused for attn out)
    //   [16777216,   23068672)  wq|wk|wv bf16     [3072][1024]
    //   [23068672,   25165824)  wo bf16           [1024][1024]
    //   [25165824,   75497472)  qkv bf16          [8192][3072]
    //   [75497472,   92274688)  V^T bf16          [64 heads][64 dv][2048 s]
    ushort_t* xb   = (ushort_t*)(ws);
    ushort_t* wqkv = (ushort_t*)(ws + 16777216);
    ushort_t* wob  = (ushort_t*)(ws + 23068672);
    ushort_t* qkv  = (ushort_t*)(ws + 25165824);
    ushort_t* vtb  = (ushort_t*)(ws + 75497472);
    ushort_t* attn = xb;   // x no longer needed after QKV GEMM
    float* out = (float*)d_out;

    conv_bf16<<<8192, 256, 0, stream>>>(x,  xb,             8388608);
    conv_bf16<<<1024, 256, 0, stream>>>(wq, wqkv,           1048576);
    conv_bf16<<<1024, 256, 0, stream>>>(wk, wqkv + 1048576, 1048576);
    conv_bf16<<<1024, 256, 0, stream>>>(wv, wqkv + 2097152, 1048576);
    conv_bf16<<<1024, 256, 0, stream>>>(wo, wob,            1048576);

    gemm_nt<1><<<dim3(24, 64), 256, 0, stream>>>(xb, wqkv, qkv, nullptr,
                                                 8192, 3072, 1024, 3072);
    transpose_v<<<dim3(32, 64), 256, 0, stream>>>(qkv, vtb);
    attn_fwd<<<dim3(16, 64), 256, 0, stream>>>(qkv, vtb, attn);
    gemm_nt<0><<<dim3(8, 64), 256, 0, stream>>>(attn, wob, out, bo,
                                                8192, 1024, 1024, 1024);
}